// Round 8
// baseline (590.882 us; speedup 1.0000x reference)
//
#include <hip/hip_runtime.h>

#define HEADS 4

// ---------------- GEMM: C[M,Ncols] = A[M,K] @ B[K,Ncols] ----------------
__global__ __launch_bounds__(256)
void gemm_k(const float* __restrict__ A, const float* __restrict__ B,
            float* __restrict__ C, int M, int K, int Ncols) {
    constexpr int BM = 128, BN = 32, BK = 32;
    __shared__ float As[BK][BM];
    __shared__ float Bs[BK][BN];
    const int m0 = blockIdx.x * BM;
    const int n0 = blockIdx.y * BN;
    const int tid = threadIdx.x;
    const int ty = tid >> 3;
    const int tx = tid & 7;
    float acc[4][4] = {};
    for (int kt = 0; kt < K; kt += BK) {
        #pragma unroll
        for (int it = 0; it < 4; ++it) {
            int i = tid + 256 * it;
            int row = i >> 3;
            int kc = (i & 7) * 4;
            int grow = m0 + row;
            float4 v = make_float4(0.f, 0.f, 0.f, 0.f);
            if (grow < M)
                v = *(const float4*)&A[(size_t)grow * K + kt + kc];
            As[kc + 0][row] = v.x;
            As[kc + 1][row] = v.y;
            As[kc + 2][row] = v.z;
            As[kc + 3][row] = v.w;
        }
        {
            int kr = tid >> 3;
            int nc = (tid & 7) * 4;
            *(float4*)&Bs[kr][nc] =
                *(const float4*)&B[(size_t)(kt + kr) * Ncols + n0 + nc];
        }
        __syncthreads();
        #pragma unroll
        for (int k = 0; k < BK; ++k) {
            float4 av = *(const float4*)&As[k][ty * 4];
            float4 bv = *(const float4*)&Bs[k][tx * 4];
            float a[4] = {av.x, av.y, av.z, av.w};
            float b[4] = {bv.x, bv.y, bv.z, bv.w};
            #pragma unroll
            for (int i = 0; i < 4; ++i)
                #pragma unroll
                for (int j = 0; j < 4; ++j)
                    acc[i][j] += a[i] * b[j];
        }
        __syncthreads();
    }
    #pragma unroll
    for (int i = 0; i < 4; ++i) {
        int grow = m0 + ty * 4 + i;
        if (grow < M) {
            float4 v = make_float4(acc[i][0], acc[i][1], acc[i][2], acc[i][3]);
            *(float4*)&C[(size_t)grow * Ncols + n0 + tx * 4] = v;
        }
    }
}

// ---------------- per-node alpha + sigmoid ----------------
__global__ __launch_bounds__(256)
void alpha_k(const float* __restrict__ xh, const float* __restrict__ attq,
             float* __restrict__ sa, int n, int C, int HC) {
    const int t = blockIdx.x * blockDim.x + threadIdx.x;
    if (t >= n * HEADS) return;
    const int nd = t >> 2, h = t & 3;
    const float* xr = &xh[(size_t)nd * HC + h * C];
    const float* q = &attq[h * C];
    float s = 0.f;
    for (int c = 0; c < C; c += 4) {
        float4 a = *(const float4*)&xr[c];
        float4 b = *(const float4*)&q[c];
        s += a.x * b.x + a.y * b.y + a.z * b.z + a.w * b.w;
    }
    sa[t] = 1.0f / (1.0f + __expf(-s));
}

// ---------------- CSR build (dst-sorted), once per launch ----------------
__global__ __launch_bounds__(256)
void hist_k(const int* __restrict__ dst, int* __restrict__ deg, int E) {
    int e = blockIdx.x * 256 + threadIdx.x;
    if (e < E) atomicAdd(&deg[dst[e]], 1);
}

__global__ __launch_bounds__(256)
void scan1_k(const int* __restrict__ deg, int* __restrict__ ro,
             int* __restrict__ bsum, int n) {
    __shared__ int s[256];
    int i = blockIdx.x * 256 + threadIdx.x;
    int v = (i < n) ? deg[i] : 0;
    s[threadIdx.x] = v;
    __syncthreads();
    for (int off = 1; off < 256; off <<= 1) {
        int t = (threadIdx.x >= off) ? s[threadIdx.x - off] : 0;
        __syncthreads();
        s[threadIdx.x] += t;
        __syncthreads();
    }
    if (i < n) ro[i] = s[threadIdx.x] - v;
    if (threadIdx.x == 255) bsum[blockIdx.x] = s[255];
}

__global__ __launch_bounds__(256)
void scan2_k(int* __restrict__ bsum, int nb) {
    __shared__ int s[256];
    int v = (threadIdx.x < nb) ? bsum[threadIdx.x] : 0;
    s[threadIdx.x] = v;
    __syncthreads();
    for (int off = 1; off < 256; off <<= 1) {
        int t = (threadIdx.x >= off) ? s[threadIdx.x - off] : 0;
        __syncthreads();
        s[threadIdx.x] += t;
        __syncthreads();
    }
    if (threadIdx.x < nb) bsum[threadIdx.x] = s[threadIdx.x] - v;
}

__global__ __launch_bounds__(256)
void scan3_k(int* __restrict__ ro, int* __restrict__ cur,
             const int* __restrict__ bsum, int n, int E) {
    int i = blockIdx.x * 256 + threadIdx.x;
    if (i < n) {
        int r = ro[i] + bsum[i >> 8];
        ro[i] = r;
        cur[i] = r;
    }
    if (i == 0) ro[n] = E;
}

__global__ __launch_bounds__(256)
void scatter_idx_k(const int* __restrict__ src, const int* __restrict__ dst,
                   int* __restrict__ cur, int* __restrict__ csr_src,
                   int* __restrict__ csr_dst, int E) {
    int e = blockIdx.x * 256 + threadIdx.x;
    if (e >= E) return;
    int d = dst[e];
    int pos = atomicAdd(&cur[d], 1);
    csr_src[pos] = src[e];
    csr_dst[pos] = d;
}

// ---------------- zero accumulators for block-crossing nodes ----------------
__global__ __launch_bounds__(256)
void zinit_k(const int* __restrict__ ro, float* __restrict__ tmpnum,
             float* __restrict__ den_acc, int n, int C) {
    const int t = blockIdx.x * 256 + threadIdx.x;
    if (t >= n * 4) return;
    const int node = t >> 2, h = t & 3;
    const int s0 = ro[node], s1 = ro[node + 1];
    if ((s0 >> 6) == ((s1 - 1) >> 6)) return;  // not crossing
    den_acc[t] = 0.f;
    float* p = &tmpnum[(size_t)node * 4 * C + h * C];
    for (int i = 0; i < C; ++i) p[i] = 0.f;
}

// ---------------- fused edge-block kernel ----------------
// Grid over blocks of EPB=64 consecutive CSR edges (dst-sorted).
//  phase 1: stage the 64 src rows into LDS (fully parallel gather)
//  phase 2: per-(edge,head) logits from LDS (xd row via L1 broadcast)
//  phase 3: segmented aggregation per node from LDS; interior nodes write
//           final output directly; crossing nodes atomicAdd raw partials.
template <int C, bool CONCAT>
__global__ __launch_bounds__((C == 32) ? 256 : 320)
void edge_block_k(const int* __restrict__ ro, const int* __restrict__ csr_src,
                  const int* __restrict__ csr_dst, const float* __restrict__ xh,
                  const float* __restrict__ sa, const float* __restrict__ attv,
                  const float* __restrict__ bias, float* __restrict__ outp,
                  float* __restrict__ tmpnum, float* __restrict__ den_acc,
                  int E) {
    constexpr int HC = 4 * C;
    constexpr int QH4 = C / 4;              // float4 per head-quarter
    constexpr int EPB = 64;
    constexpr int T = (C == 32) ? 256 : 320;
    constexpr int NSLOT = T / C;            // 8
    __shared__ float4 rows[EPB][C + 1];
    __shared__ float wbuf[EPB * 4];
    __shared__ int sib[EPB];
    __shared__ int dstb[EPB];
    __shared__ float avs[HC];

    const int bstart = blockIdx.x * EPB;
    const int bend = min(bstart + EPB, E);
    const int cnt = bend - bstart;
    const float4* __restrict__ xh4 = (const float4*)xh;

    for (int i = threadIdx.x; i < HC; i += T) avs[i] = attv[i];
    for (int i = threadIdx.x; i < cnt; i += T) {
        sib[i] = csr_src[bstart + i];
        dstb[i] = csr_dst[bstart + i];
    }
    __syncthreads();
    // ---- phase 1: stage src rows ----
    for (int i = threadIdx.x; i < cnt * C; i += T) {
        const int e = i / C, q = i - e * C;
        rows[e][q] = xh4[(size_t)sib[e] * C + q];
    }
    __syncthreads();
    // ---- phase 2: logits ----
    if (threadIdx.x < cnt * 4) {
        const int e = threadIdx.x >> 2, h = threadIdx.x & 3;
        const int d = dstb[e], si = sib[e];
        const float wa = 1.0f - fabsf(sa[d * 4 + h] - sa[si * 4 + h]);
        float wb = 0.f;
        #pragma unroll
        for (int i = 0; i < QH4; ++i) {
            const float4 a = rows[e][h * QH4 + i];
            const float4 b = xh4[(size_t)d * C + h * QH4 + i];
            const float4 v = ((const float4*)avs)[h * QH4 + i];
            float t;
            t = a.x + b.x; t = t > 0.f ? t : 0.01f * t; wb += v.x * t;
            t = a.y + b.y; t = t > 0.f ? t : 0.01f * t; wb += v.y * t;
            t = a.z + b.z; t = t > 0.f ? t : 0.01f * t; wb += v.z * t;
            t = a.w + b.w; t = t > 0.f ? t : 0.01f * t; wb += v.w * t;
        }
        wbuf[threadIdx.x] = __expf(fminf(wa * wb, 60.f));
    }
    __syncthreads();
    // ---- phase 3: segmented aggregation ----
    const int slot = threadIdx.x / C;
    const int q = threadIdx.x - slot * C;
    const int h_a = q / QH4;
    const int n0 = dstb[0], n1 = dstb[cnt - 1];
    for (int node = n0 + slot; node <= n1; node += NSLOT) {
        const int s0g = ro[node], s1g = ro[node + 1];
        const int lo = max(s0g, bstart) - bstart;
        const int hi = min(s1g, bend) - bstart;
        float4 acc = make_float4(0.f, 0.f, 0.f, 0.f);
        float den = 0.f;
        for (int j = lo; j < hi; ++j) {
            const float w = wbuf[j * 4 + h_a];
            const float4 v = rows[j][q];
            den += w;
            acc.x += w * v.x;
            acc.y += w * v.y;
            acc.z += w * v.z;
            acc.w += w * v.w;
        }
        const bool interior = (s0g >= bstart) && (s1g <= bend);
        if (interior) {
            const float inv = 1.0f / (den + 1e-20f);
            if (CONCAT) {
                const float4 b = ((const float4*)bias)[q];
                float4 v = make_float4(acc.x * inv + b.x, acc.y * inv + b.y,
                                       acc.z * inv + b.z, acc.w * inv + b.w);
                v.x = v.x > 0.f ? v.x : __expf(v.x) - 1.0f;
                v.y = v.y > 0.f ? v.y : __expf(v.y) - 1.0f;
                v.z = v.z > 0.f ? v.z : __expf(v.z) - 1.0f;
                v.w = v.w > 0.f ? v.w : __expf(v.w) - 1.0f;
                *(float4*)&outp[(size_t)node * HC + q * 4] = v;
            } else {
                // write normalized per-head values; finalize does head-mean
                float4 v = make_float4(acc.x * inv, acc.y * inv,
                                       acc.z * inv, acc.w * inv);
                *(float4*)&tmpnum[(size_t)node * HC + q * 4] = v;
            }
        } else {
            float* base = &tmpnum[(size_t)node * HC + q * 4];
            atomicAdd(base + 0, acc.x);
            atomicAdd(base + 1, acc.y);
            atomicAdd(base + 2, acc.z);
            atomicAdd(base + 3, acc.w);
            if (q == h_a * QH4) atomicAdd(&den_acc[node * 4 + h_a], den);
        }
    }
}

// ---------------- finalize layer-1 (crossing nodes only) ----------------
template <int C>
__global__ __launch_bounds__(256)
void fin1_k(const int* __restrict__ ro, const float* __restrict__ tmpnum,
            const float* __restrict__ den_acc, const float* __restrict__ bias,
            float* __restrict__ outp, int n) {
    constexpr int HC = 4 * C;
    const int t = blockIdx.x * 256 + threadIdx.x;
    if (t >= n * C) return;
    const int node = t / C, q = t - node * C;
    const int s0 = ro[node], s1 = ro[node + 1];
    if ((s0 >> 6) == ((s1 - 1) >> 6)) return;  // interior: already written
    const int h = q / (C / 4);
    const float inv = 1.0f / (den_acc[node * 4 + h] + 1e-20f);
    const float4 a = *(const float4*)&tmpnum[(size_t)node * HC + q * 4];
    const float4 b = ((const float4*)bias)[q];
    float4 v = make_float4(a.x * inv + b.x, a.y * inv + b.y,
                           a.z * inv + b.z, a.w * inv + b.w);
    v.x = v.x > 0.f ? v.x : __expf(v.x) - 1.0f;
    v.y = v.y > 0.f ? v.y : __expf(v.y) - 1.0f;
    v.z = v.z > 0.f ? v.z : __expf(v.z) - 1.0f;
    v.w = v.w > 0.f ? v.w : __expf(v.w) - 1.0f;
    *(float4*)&outp[(size_t)node * HC + q * 4] = v;
}

// ---------------- finalize layer-2 (head-mean for all nodes) ----------------
template <int C>
__global__ __launch_bounds__(256)
void fin2_k(const int* __restrict__ ro, const float* __restrict__ tmpnum,
            const float* __restrict__ den_acc, const float* __restrict__ bias,
            float* __restrict__ outp, int n) {
    constexpr int HC = 4 * C;
    constexpr int Q4 = C / 4;  // output float4s per node
    const int t = blockIdx.x * 256 + threadIdx.x;
    if (t >= n * Q4) return;
    const int node = t / Q4, q4 = t - node * Q4;
    const int s0 = ro[node], s1 = ro[node + 1];
    const bool crossing = (s0 >> 6) != ((s1 - 1) >> 6);
    float4 sum = make_float4(0.f, 0.f, 0.f, 0.f);
    #pragma unroll
    for (int h = 0; h < 4; ++h) {
        float4 a = *(const float4*)&tmpnum[(size_t)node * HC + h * C + q4 * 4];
        float s = 1.0f;
        if (crossing) s = 1.0f / (den_acc[node * 4 + h] + 1e-20f);
        sum.x += a.x * s;
        sum.y += a.y * s;
        sum.z += a.z * s;
        sum.w += a.w * s;
    }
    const float4 b = ((const float4*)bias)[q4];
    float4 v = make_float4(0.25f * sum.x + b.x, 0.25f * sum.y + b.y,
                           0.25f * sum.z + b.z, 0.25f * sum.w + b.w);
    *(float4*)&outp[(size_t)node * C + q4 * 4] = v;
}

extern "C" void kernel_launch(void* const* d_in, const int* in_sizes, int n_in,
                              void* d_out, int out_size, void* d_ws, size_t ws_size,
                              hipStream_t stream) {
    const float* x      = (const float*)d_in[0];
    const int*   src    = (const int*)d_in[1];
    const int*   dst    = (const int*)d_in[2];
    const float* lin1   = (const float*)d_in[3];
    const float* att_q1 = (const float*)d_in[4];
    const float* att_v1 = (const float*)d_in[5];
    const float* bias1  = (const float*)d_in[6];
    const float* lin2   = (const float*)d_in[7];
    const float* att_q2 = (const float*)d_in[8];
    const float* att_v2 = (const float*)d_in[9];
    const float* bias2  = (const float*)d_in[10];
    float* outp = (float*)d_out;

    const int n = in_sizes[0] / 256;
    const int E = in_sizes[1];
    const int nh = n * HEADS;
    const int NB = (n + 255) / 256;

    char* wsb = (char*)d_ws;
    size_t o = 0;
    float* xh      = (float*)(wsb + o); o += (size_t)n * 160 * 4;
    float* accb    = (float*)(wsb + o); o += (size_t)n * 160 * 4;
    float* tmpnum  = (float*)(wsb + o); o += (size_t)n * 160 * 4;
    float* sa      = (float*)(wsb + o); o += (size_t)nh * 4;
    float* den_acc = (float*)(wsb + o); o += (size_t)nh * 4;
    int* csr_src   = (int*)(wsb + o); o += (size_t)E * 4;
    int* csr_dst   = (int*)(wsb + o); o += (size_t)E * 4;
    int* deg       = (int*)(wsb + o); o += (size_t)n * 4;
    int* ro        = (int*)(wsb + o); o += (size_t)(n + 1) * 4;
    int* cur       = (int*)(wsb + o); o += (size_t)n * 4;
    int* bsum      = (int*)(wsb + o); o += 256 * 4;

    dim3 blk(256);
    const int EG = (E + 255) / 256;
    const int EB = (E + 63) / 64;  // edge blocks

    // ---- CSR build (dst is layer-invariant: build once, use twice) ----
    hipMemsetAsync(deg, 0, (size_t)n * 4, stream);
    hist_k<<<EG, blk, 0, stream>>>(dst, deg, E);
    scan1_k<<<NB, blk, 0, stream>>>(deg, ro, bsum, n);
    scan2_k<<<1, blk, 0, stream>>>(bsum, NB);
    scan3_k<<<NB, blk, 0, stream>>>(ro, cur, bsum, n, E);
    scatter_idx_k<<<EG, blk, 0, stream>>>(src, dst, cur, csr_src, csr_dst, E);

    // ================= layer 1: C=32, HC=128, K=256 =================
    gemm_k<<<dim3((n + 127) / 128, 128 / 32), blk, 0, stream>>>(x, lin1, xh, n, 256, 128);
    alpha_k<<<(nh + 255) / 256, blk, 0, stream>>>(xh, att_q1, sa, n, 32, 128);
    zinit_k<<<(nh + 255) / 256, blk, 0, stream>>>(ro, tmpnum, den_acc, n, 32);
    edge_block_k<32, true><<<EB, dim3(256), 0, stream>>>(
        ro, csr_src, csr_dst, xh, sa, att_v1, bias1, accb, tmpnum, den_acc, E);
    fin1_k<32><<<(n * 32 + 255) / 256, blk, 0, stream>>>(ro, tmpnum, den_acc, bias1, accb, n);

    // ================= layer 2: C=40, HC=160, K=128 =================
    gemm_k<<<dim3((n + 127) / 128, 160 / 32), blk, 0, stream>>>(accb, lin2, xh, n, 128, 160);
    alpha_k<<<(nh + 255) / 256, blk, 0, stream>>>(xh, att_q2, sa, n, 40, 160);
    zinit_k<<<(nh + 255) / 256, blk, 0, stream>>>(ro, tmpnum, den_acc, n, 40);
    edge_block_k<40, false><<<EB, dim3(320), 0, stream>>>(
        ro, csr_src, csr_dst, xh, sa, att_v2, bias2, outp, tmpnum, den_acc, E);
    fin2_k<40><<<(n * 10 + 255) / 256, blk, 0, stream>>>(ro, tmpnum, den_acc, bias2, outp, n);
}

// Round 9
// 397.822 us; speedup vs baseline: 1.4853x; 1.4853x over previous
//
#include <hip/hip_runtime.h>
#include <hip/hip_fp16.h>

#define HEADS 4

// load 4 consecutive halfs (8B aligned) -> float4
__device__ __forceinline__ float4 ldh4(const __half* p) {
    const uint2 u = *(const uint2*)p;
    const float2 a = __half22float2(*(const __half2*)&u.x);
    const float2 b = __half22float2(*(const __half2*)&u.y);
    return make_float4(a.x, a.y, b.x, b.y);
}

// ---------------- GEMM: C[M,N] = A[M,K] @ B[K,N], fp16 output ----------------
__global__ __launch_bounds__(256)
void gemm_k(const float* __restrict__ A, const float* __restrict__ B,
            __half* __restrict__ Cout, int M, int K, int Ncols) {
    constexpr int BM = 128, BN = 32, BK = 32;
    __shared__ float As[BK][BM];
    __shared__ float Bs[BK][BN];
    const int m0 = blockIdx.x * BM;
    const int n0 = blockIdx.y * BN;
    const int tid = threadIdx.x;
    const int ty = tid >> 3;
    const int tx = tid & 7;
    float acc[4][4] = {};
    for (int kt = 0; kt < K; kt += BK) {
        #pragma unroll
        for (int it = 0; it < 4; ++it) {
            int i = tid + 256 * it;
            int row = i >> 3;
            int kc = (i & 7) * 4;
            int grow = m0 + row;
            float4 v = make_float4(0.f, 0.f, 0.f, 0.f);
            if (grow < M)
                v = *(const float4*)&A[(size_t)grow * K + kt + kc];
            As[kc + 0][row] = v.x;
            As[kc + 1][row] = v.y;
            As[kc + 2][row] = v.z;
            As[kc + 3][row] = v.w;
        }
        {
            int kr = tid >> 3;
            int nc = (tid & 7) * 4;
            *(float4*)&Bs[kr][nc] =
                *(const float4*)&B[(size_t)(kt + kr) * Ncols + n0 + nc];
        }
        __syncthreads();
        #pragma unroll
        for (int k = 0; k < BK; ++k) {
            float4 av = *(const float4*)&As[k][ty * 4];
            float4 bv = *(const float4*)&Bs[k][tx * 4];
            float a[4] = {av.x, av.y, av.z, av.w};
            float b[4] = {bv.x, bv.y, bv.z, bv.w};
            #pragma unroll
            for (int i = 0; i < 4; ++i)
                #pragma unroll
                for (int j = 0; j < 4; ++j)
                    acc[i][j] += a[i] * b[j];
        }
        __syncthreads();
    }
    #pragma unroll
    for (int i = 0; i < 4; ++i) {
        int grow = m0 + ty * 4 + i;
        if (grow < M) {
            __half2 h01 = __floats2half2_rn(acc[i][0], acc[i][1]);
            __half2 h23 = __floats2half2_rn(acc[i][2], acc[i][3]);
            uint2 u;
            u.x = *(unsigned int*)&h01;
            u.y = *(unsigned int*)&h23;
            *(uint2*)&Cout[(size_t)grow * Ncols + n0 + tx * 4] = u;
        }
    }
}

// ---------------- per-node alpha + sigmoid (fp16 xh) ----------------
__global__ __launch_bounds__(256)
void alpha_k(const __half* __restrict__ xh, const float* __restrict__ attq,
             float* __restrict__ sa, int n, int C, int HC) {
    const int t = blockIdx.x * blockDim.x + threadIdx.x;
    if (t >= n * HEADS) return;
    const int nd = t >> 2, h = t & 3;
    const __half* xr = &xh[(size_t)nd * HC + h * C];
    const float* q = &attq[h * C];
    float s = 0.f;
    for (int c = 0; c < C; c += 4) {
        float4 a = ldh4(&xr[c]);
        float4 b = *(const float4*)&q[c];
        s += a.x * b.x + a.y * b.y + a.z * b.z + a.w * b.w;
    }
    sa[t] = 1.0f / (1.0f + __expf(-s));
}

// ---------------- CSR build (dst-sorted), once per launch ----------------
__global__ __launch_bounds__(256)
void hist_k(const int* __restrict__ dst, int* __restrict__ deg, int E) {
    int e = blockIdx.x * 256 + threadIdx.x;
    if (e < E) atomicAdd(&deg[dst[e]], 1);
}

__global__ __launch_bounds__(256)
void scan1_k(const int* __restrict__ deg, int* __restrict__ ro,
             int* __restrict__ bsum, int n) {
    __shared__ int s[256];
    int i = blockIdx.x * 256 + threadIdx.x;
    int v = (i < n) ? deg[i] : 0;
    s[threadIdx.x] = v;
    __syncthreads();
    for (int off = 1; off < 256; off <<= 1) {
        int t = (threadIdx.x >= off) ? s[threadIdx.x - off] : 0;
        __syncthreads();
        s[threadIdx.x] += t;
        __syncthreads();
    }
    if (i < n) ro[i] = s[threadIdx.x] - v;
    if (threadIdx.x == 255) bsum[blockIdx.x] = s[255];
}

__global__ __launch_bounds__(256)
void scan2_k(int* __restrict__ bsum, int nb) {
    __shared__ int s[256];
    int v = (threadIdx.x < nb) ? bsum[threadIdx.x] : 0;
    s[threadIdx.x] = v;
    __syncthreads();
    for (int off = 1; off < 256; off <<= 1) {
        int t = (threadIdx.x >= off) ? s[threadIdx.x - off] : 0;
        __syncthreads();
        s[threadIdx.x] += t;
        __syncthreads();
    }
    if (threadIdx.x < nb) bsum[threadIdx.x] = s[threadIdx.x] - v;
}

__global__ __launch_bounds__(256)
void scan3_k(int* __restrict__ ro, int* __restrict__ cur,
             const int* __restrict__ bsum, int n, int E) {
    int i = blockIdx.x * 256 + threadIdx.x;
    if (i < n) {
        int r = ro[i] + bsum[i >> 8];
        ro[i] = r;
        cur[i] = r;
    }
    if (i == 0) ro[n] = E;
}

__global__ __launch_bounds__(256)
void scatter_idx_k(const int* __restrict__ src, const int* __restrict__ dst,
                   int* __restrict__ cur, int* __restrict__ csr_src, int E) {
    int e = blockIdx.x * 256 + threadIdx.x;
    if (e >= E) return;
    int d = dst[e];
    int pos = atomicAdd(&cur[d], 1);
    csr_src[pos] = src[e];
}

// ---------------- fused logit+softmax+aggregate+epilogue (fp16 xh) ----------
// R5 structure (best measured): one wave per node, 64-edge super-chunks
// staged through LDS; logit passes 16 edges x 4 heads; agg loop 4 independent
// row gathers per iteration, DUAL split for C=32.
template <int C, bool CONCAT>
__global__ __launch_bounds__(256)
void fused_edge_k(const int* __restrict__ ro, const int* __restrict__ csr_src,
                  const __half* __restrict__ xh, const float* __restrict__ sa,
                  const float* __restrict__ attv, const float* __restrict__ bias,
                  float* __restrict__ outp, int n) {
    constexpr int HC = 4 * C;
    constexpr int QH = C / 4;        // 4-half chunks per head quarter
    constexpr int CHUNK = 64;        // edges per super-chunk
    constexpr bool DUAL = (C <= 32);
    const int wid = threadIdx.x >> 6;
    const int lane = threadIdx.x & 63;
    const int node = blockIdx.x * 4 + wid;

    __shared__ float wbuf[4][CHUNK * 4];
    __shared__ int sibuf[4][CHUNK];
    __shared__ float avs[HC];
    for (int i = threadIdx.x; i < HC; i += 256) avs[i] = attv[i];
    __syncthreads();
    if (node >= n) return;

    const float4* __restrict__ avs4 = (const float4*)avs;
    const int s0 = ro[node], s1 = ro[node + 1];

    // logit mapping
    const int e_loc = lane >> 2;
    const int h_l = lane & 3;
    const float sad = sa[node * 4 + h_l];

    // aggregation mapping
    const int half_ = DUAL ? (lane >> 5) : 0;
    const int q = DUAL ? (lane & 31) : lane;
    const int h_a = (q < C) ? (q / QH) : 0;

    float4 acc = make_float4(0.f, 0.f, 0.f, 0.f);
    float ssum = 0.f;

    for (int base = s0; base < s1; base += CHUNK) {
        const int cnt = min(CHUNK, s1 - base);
        const int npass = (cnt + 15) >> 4;
        // ---- logit passes: 16 edges x 4 heads per pass ----
        for (int p = 0; p < npass; ++p) {
            const int eidx = p * 16 + e_loc;
            const int j = base + eidx;
            float w = 0.f;
            int si = 0;
            if (j < s1) {
                si = csr_src[j];
                const float sas = sa[si * 4 + h_l];
                const float wa = 1.0f - fabsf(sad - sas);
                const __half* xs = &xh[(size_t)si * HC + h_l * C];
                const __half* xd = &xh[(size_t)node * HC + h_l * C];
                float wb = 0.f;
                #pragma unroll
                for (int i = 0; i < QH; ++i) {
                    const float4 a = ldh4(&xs[i * 4]);
                    const float4 b = ldh4(&xd[i * 4]);
                    const float4 v = avs4[h_l * QH + i];
                    float t0 = a.x + b.x; t0 = t0 > 0.f ? t0 : 0.01f * t0;
                    float t1 = a.y + b.y; t1 = t1 > 0.f ? t1 : 0.01f * t1;
                    float t2 = a.z + b.z; t2 = t2 > 0.f ? t2 : 0.01f * t2;
                    float t3 = a.w + b.w; t3 = t3 > 0.f ? t3 : 0.01f * t3;
                    wb += v.x * t0 + v.y * t1 + v.z * t2 + v.w * t3;
                }
                w = __expf(fminf(wa * wb, 60.f));  // inf-guard only
                ssum += w;
            }
            wbuf[wid][eidx * 4 + h_l] = w;
            if (h_l == 0) sibuf[wid][eidx] = si;
        }
        // ---- aggregation: padded slots carry w=0/si=0, no guards ----
        const int padded = npass << 4;
        if (q < C) {
            if (DUAL) {
                for (int i = 0; i < padded; i += 8) {
                    const int e0 = i + half_, e1 = i + half_ + 2;
                    const int e2 = i + half_ + 4, e3 = i + half_ + 6;
                    const int i0 = sibuf[wid][e0], i1 = sibuf[wid][e1];
                    const int i2 = sibuf[wid][e2], i3 = sibuf[wid][e3];
                    const float w0 = wbuf[wid][e0 * 4 + h_a];
                    const float w1 = wbuf[wid][e1 * 4 + h_a];
                    const float w2 = wbuf[wid][e2 * 4 + h_a];
                    const float w3 = wbuf[wid][e3 * 4 + h_a];
                    const float4 v0 = ldh4(&xh[(size_t)i0 * HC + q * 4]);
                    const float4 v1 = ldh4(&xh[(size_t)i1 * HC + q * 4]);
                    const float4 v2 = ldh4(&xh[(size_t)i2 * HC + q * 4]);
                    const float4 v3 = ldh4(&xh[(size_t)i3 * HC + q * 4]);
                    acc.x += w0 * v0.x + w1 * v1.x + w2 * v2.x + w3 * v3.x;
                    acc.y += w0 * v0.y + w1 * v1.y + w2 * v2.y + w3 * v3.y;
                    acc.z += w0 * v0.z + w1 * v1.z + w2 * v2.z + w3 * v3.z;
                    acc.w += w0 * v0.w + w1 * v1.w + w2 * v2.w + w3 * v3.w;
                }
            } else {
                for (int i = 0; i < padded; i += 4) {
                    const int i0 = sibuf[wid][i],     i1 = sibuf[wid][i + 1];
                    const int i2 = sibuf[wid][i + 2], i3 = sibuf[wid][i + 3];
                    const float w0 = wbuf[wid][(i + 0) * 4 + h_a];
                    const float w1 = wbuf[wid][(i + 1) * 4 + h_a];
                    const float w2 = wbuf[wid][(i + 2) * 4 + h_a];
                    const float w3 = wbuf[wid][(i + 3) * 4 + h_a];
                    const float4 v0 = ldh4(&xh[(size_t)i0 * HC + q * 4]);
                    const float4 v1 = ldh4(&xh[(size_t)i1 * HC + q * 4]);
                    const float4 v2 = ldh4(&xh[(size_t)i2 * HC + q * 4]);
                    const float4 v3 = ldh4(&xh[(size_t)i3 * HC + q * 4]);
                    acc.x += w0 * v0.x + w1 * v1.x + w2 * v2.x + w3 * v3.x;
                    acc.y += w0 * v0.y + w1 * v1.y + w2 * v2.y + w3 * v3.y;
                    acc.z += w0 * v0.z + w1 * v1.z + w2 * v2.z + w3 * v3.z;
                    acc.w += w0 * v0.w + w1 * v1.w + w2 * v2.w + w3 * v3.w;
                }
            }
        }
    }

    // combine dual halves
    if (DUAL) {
        acc.x += __shfl_xor(acc.x, 32, 64);
        acc.y += __shfl_xor(acc.y, 32, 64);
        acc.z += __shfl_xor(acc.z, 32, 64);
        acc.w += __shfl_xor(acc.w, 32, 64);
    }

    // per-head sum of weights: reduce across lanes sharing (lane & 3)
    #pragma unroll
    for (int off = 4; off < 64; off <<= 1) ssum += __shfl_xor(ssum, off, 64);
    const float stot = __shfl(ssum, h_a, 64);
    const float inv = 1.0f / (stot + 1e-20f);
    acc.x *= inv; acc.y *= inv; acc.z *= inv; acc.w *= inv;

    if (CONCAT) {
        if (q < C && half_ == 0) {
            const float4 b = ((const float4*)bias)[q];
            float4 v = make_float4(acc.x + b.x, acc.y + b.y, acc.z + b.z, acc.w + b.w);
            v.x = v.x > 0.f ? v.x : __expf(v.x) - 1.0f;
            v.y = v.y > 0.f ? v.y : __expf(v.y) - 1.0f;
            v.z = v.z > 0.f ? v.z : __expf(v.z) - 1.0f;
            v.w = v.w > 0.f ? v.w : __expf(v.w) - 1.0f;
            *(float4*)&outp[(size_t)node * HC + q * 4] = v;
        }
    } else {
        // head-mean via shuffles: lanes q<QH gather the other 3 heads' chunks
        const int qq = (q < QH) ? q : 0;
        const float x1 = __shfl(acc.x, qq + QH, 64);
        const float y1 = __shfl(acc.y, qq + QH, 64);
        const float z1 = __shfl(acc.z, qq + QH, 64);
        const float w1 = __shfl(acc.w, qq + QH, 64);
        const float x2 = __shfl(acc.x, qq + 2 * QH, 64);
        const float y2 = __shfl(acc.y, qq + 2 * QH, 64);
        const float z2 = __shfl(acc.z, qq + 2 * QH, 64);
        const float w2 = __shfl(acc.w, qq + 2 * QH, 64);
        const float x3 = __shfl(acc.x, qq + 3 * QH, 64);
        const float y3 = __shfl(acc.y, qq + 3 * QH, 64);
        const float z3 = __shfl(acc.z, qq + 3 * QH, 64);
        const float w3 = __shfl(acc.w, qq + 3 * QH, 64);
        if (q < QH && half_ == 0) {
            const float4 b = ((const float4*)bias)[q];
            float4 v;
            v.x = 0.25f * (acc.x + x1 + x2 + x3) + b.x;
            v.y = 0.25f * (acc.y + y1 + y2 + y3) + b.y;
            v.z = 0.25f * (acc.z + z1 + z2 + z3) + b.z;
            v.w = 0.25f * (acc.w + w1 + w2 + w3) + b.w;
            *(float4*)&outp[(size_t)node * C + q * 4] = v;
        }
    }
}

extern "C" void kernel_launch(void* const* d_in, const int* in_sizes, int n_in,
                              void* d_out, int out_size, void* d_ws, size_t ws_size,
                              hipStream_t stream) {
    const float* x      = (const float*)d_in[0];
    const int*   src    = (const int*)d_in[1];
    const int*   dst    = (const int*)d_in[2];
    const float* lin1   = (const float*)d_in[3];
    const float* att_q1 = (const float*)d_in[4];
    const float* att_v1 = (const float*)d_in[5];
    const float* bias1  = (const float*)d_in[6];
    const float* lin2   = (const float*)d_in[7];
    const float* att_q2 = (const float*)d_in[8];
    const float* att_v2 = (const float*)d_in[9];
    const float* bias2  = (const float*)d_in[10];
    float* outp = (float*)d_out;

    const int n = in_sizes[0] / 256;
    const int E = in_sizes[1];
    const int nh = n * HEADS;
    const int NB = (n + 255) / 256;

    char* wsb = (char*)d_ws;
    size_t o = 0;
    __half* xh    = (__half*)(wsb + o); o += (size_t)n * 160 * 2;
    float* accb   = (float*)(wsb + o); o += (size_t)n * 160 * 4;
    float* sa     = (float*)(wsb + o); o += (size_t)nh * 4;
    int* csr_src  = (int*)(wsb + o); o += (size_t)E * 4;
    int* deg      = (int*)(wsb + o); o += (size_t)n * 4;
    int* ro       = (int*)(wsb + o); o += (size_t)(n + 1) * 4;
    int* cur      = (int*)(wsb + o); o += (size_t)n * 4;
    int* bsum     = (int*)(wsb + o); o += 256 * 4;

    dim3 blk(256);
    const int EG = (E + 255) / 256;

    // ---- CSR build (dst is layer-invariant: build once, use twice) ----
    hipMemsetAsync(deg, 0, (size_t)n * 4, stream);
    hist_k<<<EG, blk, 0, stream>>>(dst, deg, E);
    scan1_k<<<NB, blk, 0, stream>>>(deg, ro, bsum, n);
    scan2_k<<<1, blk, 0, stream>>>(bsum, NB);
    scan3_k<<<NB, blk, 0, stream>>>(ro, cur, bsum, n, E);
    scatter_idx_k<<<EG, blk, 0, stream>>>(src, dst, cur, csr_src, E);

    // ================= layer 1: C=32, HC=128, K=256 =================
    gemm_k<<<dim3((n + 127) / 128, 128 / 32), blk, 0, stream>>>(x, lin1, xh, n, 256, 128);
    alpha_k<<<(nh + 255) / 256, blk, 0, stream>>>(xh, att_q1, sa, n, 32, 128);
    fused_edge_k<32, true><<<(n + 3) / 4, blk, 0, stream>>>(ro, csr_src, xh, sa, att_v1, bias1, accb, n);

    // ================= layer 2: C=40, HC=160, K=128 =================
    gemm_k<<<dim3((n + 127) / 128, 160 / 32), blk, 0, stream>>>(accb, lin2, xh, n, 128, 160);
    alpha_k<<<(nh + 255) / 256, blk, 0, stream>>>(xh, att_q2, sa, n, 40, 160);
    fused_edge_k<40, false><<<(n + 3) / 4, blk, 0, stream>>>(ro, csr_src, xh, sa, att_v2, bias2, outp, n);
}

// Round 10
// 345.421 us; speedup vs baseline: 1.7106x; 1.1517x over previous
//
#include <hip/hip_runtime.h>
#include <hip/hip_fp16.h>

#define HEADS 4

typedef _Float16 v2h __attribute__((ext_vector_type(2)));

// load 4 consecutive halfs (8B aligned) -> float4
__device__ __forceinline__ float4 ldh4(const __half* p) {
    const uint2 u = *(const uint2*)p;
    const float2 a = __half22float2(*(const __half2*)&u.x);
    const float2 b = __half22float2(*(const __half2*)&u.y);
    return make_float4(a.x, a.y, b.x, b.y);
}

__device__ __forceinline__ __half2 habs2_(__half2 x) {
    unsigned u = *reinterpret_cast<unsigned*>(&x) & 0x7FFF7FFFu;
    return *reinterpret_cast<__half2*>(&u);
}

__device__ __forceinline__ float fdot2_(__half2 a, __half2 b, float c) {
    return __builtin_amdgcn_fdot2(*(v2h*)&a, *(v2h*)&b, c, false);
}

// ------------- GEMM: C[M,N] = A[M,K] @ B[K,N]; fp16 LDS + v_dot2 -----------
__global__ __launch_bounds__(256)
void gemm_k(const float* __restrict__ A, const float* __restrict__ B,
            __half* __restrict__ Cout, int M, int K, int Ncols) {
    constexpr int BM = 128, BN = 32, BK = 32;
    __shared__ v2h As2[BK / 2][BM];   // [k2][m] = {A[2k2][m], A[2k2+1][m]}
    __shared__ v2h Bs2[BK / 2][BN];   // [k2][n] = {B[2k2][n], B[2k2+1][n]}
    const int m0 = blockIdx.x * BM;
    const int n0 = blockIdx.y * BN;
    const int tid = threadIdx.x;
    const int ty = tid >> 3;
    const int tx = tid & 7;
    float acc[4][4] = {};
    for (int kt = 0; kt < K; kt += BK) {
        // stage A tile: 128 rows x 32 k, as k-paired half2, transposed
        #pragma unroll
        for (int it = 0; it < 4; ++it) {
            int i = tid + 256 * it;
            int row = i >> 3;
            int kc = (i & 7) * 4;
            int grow = m0 + row;
            float4 v = make_float4(0.f, 0.f, 0.f, 0.f);
            if (grow < M)
                v = *(const float4*)&A[(size_t)grow * K + kt + kc];
            v2h p0; p0[0] = (_Float16)v.x; p0[1] = (_Float16)v.y;
            v2h p1; p1[0] = (_Float16)v.z; p1[1] = (_Float16)v.w;
            As2[(kc >> 1) + 0][row] = p0;
            As2[(kc >> 1) + 1][row] = p1;
        }
        // stage B tile: threads 0..127, each loads rows 2k2 and 2k2+1
        if (tid < 128) {
            const int k2 = tid >> 3;
            const int n4 = (tid & 7) * 4;
            const float4 fa = *(const float4*)&B[(size_t)(kt + 2 * k2) * Ncols + n0 + n4];
            const float4 fb = *(const float4*)&B[(size_t)(kt + 2 * k2 + 1) * Ncols + n0 + n4];
            v2h q0; q0[0] = (_Float16)fa.x; q0[1] = (_Float16)fb.x;
            v2h q1; q1[0] = (_Float16)fa.y; q1[1] = (_Float16)fb.y;
            v2h q2; q2[0] = (_Float16)fa.z; q2[1] = (_Float16)fb.z;
            v2h q3; q3[0] = (_Float16)fa.w; q3[1] = (_Float16)fb.w;
            Bs2[k2][n4 + 0] = q0;
            Bs2[k2][n4 + 1] = q1;
            Bs2[k2][n4 + 2] = q2;
            Bs2[k2][n4 + 3] = q3;
        }
        __syncthreads();
        #pragma unroll
        for (int k2 = 0; k2 < BK / 2; ++k2) {
            v2h a_[4], b_[4];
            #pragma unroll
            for (int i = 0; i < 4; ++i) a_[i] = As2[k2][ty * 4 + i];
            #pragma unroll
            for (int j = 0; j < 4; ++j) b_[j] = Bs2[k2][tx * 4 + j];
            #pragma unroll
            for (int i = 0; i < 4; ++i)
                #pragma unroll
                for (int j = 0; j < 4; ++j)
                    acc[i][j] = __builtin_amdgcn_fdot2(a_[i], b_[j], acc[i][j], false);
        }
        __syncthreads();
    }
    #pragma unroll
    for (int i = 0; i < 4; ++i) {
        int grow = m0 + ty * 4 + i;
        if (grow < M) {
            __half2 h01 = __floats2half2_rn(acc[i][0], acc[i][1]);
            __half2 h23 = __floats2half2_rn(acc[i][2], acc[i][3]);
            uint2 u;
            u.x = *(unsigned int*)&h01;
            u.y = *(unsigned int*)&h23;
            *(uint2*)&Cout[(size_t)grow * Ncols + n0 + tx * 4] = u;
        }
    }
}

// ---------------- per-node alpha + sigmoid (fp16 xh) ----------------
__global__ __launch_bounds__(256)
void alpha_k(const __half* __restrict__ xh, const float* __restrict__ attq,
             float* __restrict__ sa, int n, int C, int HC) {
    const int t = blockIdx.x * blockDim.x + threadIdx.x;
    if (t >= n * HEADS) return;
    const int nd = t >> 2, h = t & 3;
    const __half* xr = &xh[(size_t)nd * HC + h * C];
    const float* q = &attq[h * C];
    float s = 0.f;
    for (int c = 0; c < C; c += 4) {
        float4 a = ldh4(&xr[c]);
        float4 b = *(const float4*)&q[c];
        s += a.x * b.x + a.y * b.y + a.z * b.z + a.w * b.w;
    }
    sa[t] = 1.0f / (1.0f + __expf(-s));
}

// ---------------- CSR build (dst-sorted), once per launch ----------------
__global__ __launch_bounds__(256)
void hist_k(const int* __restrict__ dst, int* __restrict__ deg, int E) {
    int e = blockIdx.x * 256 + threadIdx.x;
    if (e < E) atomicAdd(&deg[dst[e]], 1);
}

__global__ __launch_bounds__(256)
void scan1_k(const int* __restrict__ deg, int* __restrict__ ro,
             int* __restrict__ bsum, int n) {
    __shared__ int s[256];
    int i = blockIdx.x * 256 + threadIdx.x;
    int v = (i < n) ? deg[i] : 0;
    s[threadIdx.x] = v;
    __syncthreads();
    for (int off = 1; off < 256; off <<= 1) {
        int t = (threadIdx.x >= off) ? s[threadIdx.x - off] : 0;
        __syncthreads();
        s[threadIdx.x] += t;
        __syncthreads();
    }
    if (i < n) ro[i] = s[threadIdx.x] - v;
    if (threadIdx.x == 255) bsum[blockIdx.x] = s[255];
}

__global__ __launch_bounds__(256)
void scan2_k(int* __restrict__ bsum, int nb) {
    __shared__ int s[256];
    int v = (threadIdx.x < nb) ? bsum[threadIdx.x] : 0;
    s[threadIdx.x] = v;
    __syncthreads();
    for (int off = 1; off < 256; off <<= 1) {
        int t = (threadIdx.x >= off) ? s[threadIdx.x - off] : 0;
        __syncthreads();
        s[threadIdx.x] += t;
        __syncthreads();
    }
    if (threadIdx.x < nb) bsum[threadIdx.x] = s[threadIdx.x] - v;
}

__global__ __launch_bounds__(256)
void scan3_k(int* __restrict__ ro, int* __restrict__ cur,
             const int* __restrict__ bsum, int n, int E) {
    int i = blockIdx.x * 256 + threadIdx.x;
    if (i < n) {
        int r = ro[i] + bsum[i >> 8];
        ro[i] = r;
        cur[i] = r;
    }
    if (i == 0) ro[n] = E;
}

__global__ __launch_bounds__(256)
void scatter_idx_k(const int* __restrict__ src, const int* __restrict__ dst,
                   int* __restrict__ cur, int* __restrict__ csr_src, int E) {
    int e = blockIdx.x * 256 + threadIdx.x;
    if (e >= E) return;
    int d = dst[e];
    int pos = atomicAdd(&cur[d], 1);
    csr_src[pos] = src[e];
}

// ---------------- fused logit+softmax+aggregate+epilogue (fp16 xh) ----------
// R9 structure; logit inner loop in packed half2 with v_dot2 accumulation.
template <int C, bool CONCAT>
__global__ __launch_bounds__(256)
void fused_edge_k(const int* __restrict__ ro, const int* __restrict__ csr_src,
                  const __half* __restrict__ xh, const float* __restrict__ sa,
                  const float* __restrict__ attv, const float* __restrict__ bias,
                  float* __restrict__ outp, int n) {
    constexpr int HC = 4 * C;
    constexpr int QH = C / 4;        // 4-half chunks per head quarter
    constexpr int CHUNK = 64;        // edges per super-chunk
    constexpr bool DUAL = (C <= 32);
    const int wid = threadIdx.x >> 6;
    const int lane = threadIdx.x & 63;
    const int node = blockIdx.x * 4 + wid;

    __shared__ float wbuf[4][CHUNK * 4];
    __shared__ int sibuf[4][CHUNK];
    __shared__ __half2 avs[HC / 2];
    for (int i = threadIdx.x; i < HC / 2; i += 256)
        avs[i] = __floats2half2_rn(attv[2 * i], attv[2 * i + 1]);
    __syncthreads();
    if (node >= n) return;

    const int s0 = ro[node], s1 = ro[node + 1];

    // logit mapping
    const int e_loc = lane >> 2;
    const int h_l = lane & 3;
    const float sad = sa[node * 4 + h_l];
    const __half2 c505 = __floats2half2_rn(0.505f, 0.505f);
    const __half2 c495 = __floats2half2_rn(0.495f, 0.495f);

    // hoisted dst-row quarter as half2 (uint2 loads, no converts)
    __half2 xd[QH * 2];
    {
        const __half* p = &xh[(size_t)node * HC + h_l * C];
        #pragma unroll
        for (int i = 0; i < QH; ++i) {
            const uint2 u = *(const uint2*)&p[i * 4];
            xd[2 * i] = *(const __half2*)&u.x;
            xd[2 * i + 1] = *(const __half2*)&u.y;
        }
    }

    // aggregation mapping
    const int half_ = DUAL ? (lane >> 5) : 0;
    const int q = DUAL ? (lane & 31) : lane;
    const int h_a = (q < C) ? (q / QH) : 0;

    float4 acc = make_float4(0.f, 0.f, 0.f, 0.f);
    float ssum = 0.f;

    for (int base = s0; base < s1; base += CHUNK) {
        const int cnt = min(CHUNK, s1 - base);
        const int npass = (cnt + 15) >> 4;
        // ---- logit passes: 16 edges x 4 heads per pass, packed fp16 ----
        for (int p = 0; p < npass; ++p) {
            const int eidx = p * 16 + e_loc;
            const int j = base + eidx;
            float w = 0.f;
            int si = 0;
            if (j < s1) {
                si = csr_src[j];
                const float sas = sa[si * 4 + h_l];
                const float wa = 1.0f - fabsf(sad - sas);
                const __half* xs = &xh[(size_t)si * HC + h_l * C];
                float wb = 0.f;
                #pragma unroll
                for (int i = 0; i < QH; ++i) {
                    const uint2 u = *(const uint2*)&xs[i * 4];
                    const __half2 a0 = *(const __half2*)&u.x;
                    const __half2 a1 = *(const __half2*)&u.y;
                    const __half2 t0 = __hadd2(a0, xd[2 * i]);
                    const __half2 t1 = __hadd2(a1, xd[2 * i + 1]);
                    const __half2 l0 = __hfma2(t0, c505, __hmul2(habs2_(t0), c495));
                    const __half2 l1 = __hfma2(t1, c505, __hmul2(habs2_(t1), c495));
                    wb = fdot2_(l0, avs[h_l * QH * 2 + 2 * i], wb);
                    wb = fdot2_(l1, avs[h_l * QH * 2 + 2 * i + 1], wb);
                }
                w = __expf(fminf(wa * wb, 60.f));  // inf-guard only
                ssum += w;
            }
            wbuf[wid][eidx * 4 + h_l] = w;
            if (h_l == 0) sibuf[wid][eidx] = si;
        }
        // ---- aggregation: padded slots carry w=0/si=0, no guards ----
        const int padded = npass << 4;
        if (q < C) {
            if (DUAL) {
                for (int i = 0; i < padded; i += 8) {
                    const int e0 = i + half_, e1 = i + half_ + 2;
                    const int e2 = i + half_ + 4, e3 = i + half_ + 6;
                    const int i0 = sibuf[wid][e0], i1 = sibuf[wid][e1];
                    const int i2 = sibuf[wid][e2], i3 = sibuf[wid][e3];
                    const float w0 = wbuf[wid][e0 * 4 + h_a];
                    const float w1 = wbuf[wid][e1 * 4 + h_a];
                    const float w2 = wbuf[wid][e2 * 4 + h_a];
                    const float w3 = wbuf[wid][e3 * 4 + h_a];
                    const float4 v0 = ldh4(&xh[(size_t)i0 * HC + q * 4]);
                    const float4 v1 = ldh4(&xh[(size_t)i1 * HC + q * 4]);
                    const float4 v2 = ldh4(&xh[(size_t)i2 * HC + q * 4]);
                    const float4 v3 = ldh4(&xh[(size_t)i3 * HC + q * 4]);
                    acc.x += w0 * v0.x + w1 * v1.x + w2 * v2.x + w3 * v3.x;
                    acc.y += w0 * v0.y + w1 * v1.y + w2 * v2.y + w3 * v3.y;
                    acc.z += w0 * v0.z + w1 * v1.z + w2 * v2.z + w3 * v3.z;
                    acc.w += w0 * v0.w + w1 * v1.w + w2 * v2.w + w3 * v3.w;
                }
            } else {
                for (int i = 0; i < padded; i += 4) {
                    const int i0 = sibuf[wid][i],     i1 = sibuf[wid][i + 1];
                    const int i2 = sibuf[wid][i + 2], i3 = sibuf[wid][i + 3];
                    const float w0 = wbuf[wid][(i + 0) * 4 + h_a];
                    const float w1 = wbuf[wid][(i + 1) * 4 + h_a];
                    const float w2 = wbuf[wid][(i + 2) * 4 + h_a];
                    const float w3 = wbuf[wid][(i + 3) * 4 + h_a];
                    const float4 v0 = ldh4(&xh[(size_t)i0 * HC + q * 4]);
                    const float4 v1 = ldh4(&xh[(size_t)i1 * HC + q * 4]);
                    const float4 v2 = ldh4(&xh[(size_t)i2 * HC + q * 4]);
                    const float4 v3 = ldh4(&xh[(size_t)i3 * HC + q * 4]);
                    acc.x += w0 * v0.x + w1 * v1.x + w2 * v2.x + w3 * v3.x;
                    acc.y += w0 * v0.y + w1 * v1.y + w2 * v2.y + w3 * v3.y;
                    acc.z += w0 * v0.z + w1 * v1.z + w2 * v2.z + w3 * v3.z;
                    acc.w += w0 * v0.w + w1 * v1.w + w2 * v2.w + w3 * v3.w;
                }
            }
        }
    }

    // combine dual halves
    if (DUAL) {
        acc.x += __shfl_xor(acc.x, 32, 64);
        acc.y += __shfl_xor(acc.y, 32, 64);
        acc.z += __shfl_xor(acc.z, 32, 64);
        acc.w += __shfl_xor(acc.w, 32, 64);
    }

    // per-head sum of weights: reduce across lanes sharing (lane & 3)
    #pragma unroll
    for (int off = 4; off < 64; off <<= 1) ssum += __shfl_xor(ssum, off, 64);
    const float stot = __shfl(ssum, h_a, 64);
    const float inv = 1.0f / (stot + 1e-20f);
    acc.x *= inv; acc.y *= inv; acc.z *= inv; acc.w *= inv;

    if (CONCAT) {
        if (q < C && half_ == 0) {
            const float4 b = ((const float4*)bias)[q];
            float4 v = make_float4(acc.x + b.x, acc.y + b.y, acc.z + b.z, acc.w + b.w);
            v.x = v.x > 0.f ? v.x : __expf(v.x) - 1.0f;
            v.y = v.y > 0.f ? v.y : __expf(v.y) - 1.0f;
            v.z = v.z > 0.f ? v.z : __expf(v.z) - 1.0f;
            v.w = v.w > 0.f ? v.w : __expf(v.w) - 1.0f;
            *(float4*)&outp[(size_t)node * HC + q * 4] = v;
        }
    } else {
        // head-mean via shuffles
        const int qq = (q < QH) ? q : 0;
        const float x1 = __shfl(acc.x, qq + QH, 64);
        const float y1 = __shfl(acc.y, qq + QH, 64);
        const float z1 = __shfl(acc.z, qq + QH, 64);
        const float w1 = __shfl(acc.w, qq + QH, 64);
        const float x2 = __shfl(acc.x, qq + 2 * QH, 64);
        const float y2 = __shfl(acc.y, qq + 2 * QH, 64);
        const float z2 = __shfl(acc.z, qq + 2 * QH, 64);
        const float w2 = __shfl(acc.w, qq + 2 * QH, 64);
        const float x3 = __shfl(acc.x, qq + 3 * QH, 64);
        const float y3 = __shfl(acc.y, qq + 3 * QH, 64);
        const float z3 = __shfl(acc.z, qq + 3 * QH, 64);
        const float w3 = __shfl(acc.w, qq + 3 * QH, 64);
        if (q < QH && half_ == 0) {
            const float4 b = ((const float4*)bias)[q];
            float4 v;
            v.x = 0.25f * (acc.x + x1 + x2 + x3) + b.x;
            v.y = 0.25f * (acc.y + y1 + y2 + y3) + b.y;
            v.z = 0.25f * (acc.z + z1 + z2 + z3) + b.z;
            v.w = 0.25f * (acc.w + w1 + w2 + w3) + b.w;
            *(float4*)&outp[(size_t)node * C + q * 4] = v;
        }
    }
}

extern "C" void kernel_launch(void* const* d_in, const int* in_sizes, int n_in,
                              void* d_out, int out_size, void* d_ws, size_t ws_size,
                              hipStream_t stream) {
    const float* x      = (const float*)d_in[0];
    const int*   src    = (const int*)d_in[1];
    const int*   dst    = (const int*)d_in[2];
    const float* lin1   = (const float*)d_in[3];
    const float* att_q1 = (const float*)d_in[4];
    const float* att_v1 = (const float*)d_in[5];
    const float* bias1  = (const float*)d_in[6];
    const float* lin2   = (const float*)d_in[7];
    const float* att_q2 = (const float*)d_in[8];
    const float* att_v2 = (const float*)d_in[9];
    const float* bias2  = (const float*)d_in[10];
    float* outp = (float*)d_out;

    const int n = in_sizes[0] / 256;
    const int E = in_sizes[1];
    const int nh = n * HEADS;
    const int NB = (n + 255) / 256;

    char* wsb = (char*)d_ws;
    size_t o = 0;
    __half* xh    = (__half*)(wsb + o); o += (size_t)n * 160 * 2;
    float* accb   = (float*)(wsb + o); o += (size_t)n * 160 * 4;
    float* sa     = (float*)(wsb + o); o += (size_t)nh * 4;
    int* csr_src  = (int*)(wsb + o); o += (size_t)E * 4;
    int* deg      = (int*)(wsb + o); o += (size_t)n * 4;
    int* ro       = (int*)(wsb + o); o += (size_t)(n + 1) * 4;
    int* cur      = (int*)(wsb + o); o += (size_t)n * 4;
    int* bsum     = (int*)(wsb + o); o += 256 * 4;

    dim3 blk(256);
    const int EG = (E + 255) / 256;

    // ---- CSR build (dst is layer-invariant: build once, use twice) ----
    hipMemsetAsync(deg, 0, (size_t)n * 4, stream);
    hist_k<<<EG, blk, 0, stream>>>(dst, deg, E);
    scan1_k<<<NB, blk, 0, stream>>>(deg, ro, bsum, n);
    scan2_k<<<1, blk, 0, stream>>>(bsum, NB);
    scan3_k<<<NB, blk, 0, stream>>>(ro, cur, bsum, n, E);
    scatter_idx_k<<<EG, blk, 0, stream>>>(src, dst, cur, csr_src, E);

    // ================= layer 1: C=32, HC=128, K=256 =================
    gemm_k<<<dim3((n + 127) / 128, 128 / 32), blk, 0, stream>>>(x, lin1, xh, n, 256, 128);
    alpha_k<<<(nh + 255) / 256, blk, 0, stream>>>(xh, att_q1, sa, n, 32, 128);
    fused_edge_k<32, true><<<(n + 3) / 4, blk, 0, stream>>>(ro, csr_src, xh, sa, att_v1, bias1, accb, n);

    // ================= layer 2: C=40, HC=160, K=128 =================
    gemm_k<<<dim3((n + 127) / 128, 160 / 32), blk, 0, stream>>>(accb, lin2, xh, n, 128, 160);
    alpha_k<<<(nh + 255) / 256, blk, 0, stream>>>(xh, att_q2, sa, n, 40, 160);
    fused_edge_k<40, false><<<(n + 3) / 4, blk, 0, stream>>>(ro, csr_src, xh, sa, att_v2, bias2, outp, n);
}